// Round 14
// baseline (501.113 us; speedup 1.0000x reference)
//
#include <hip/hip_runtime.h>
#include <hip/hip_bf16.h>

#define NN 16384
#define DD 128
#define KP1 11
#define NSPLIT 16
#define CBLK 32
#define COLS_PER_SPLIT (NN / NSPLIT)   /* 1024 */
#define NITER (COLS_PER_SPLIT / CBLK)  /* 32 */

typedef __attribute__((ext_vector_type(8))) short bf16x8;
typedef __attribute__((ext_vector_type(4))) float f32x4;
typedef __attribute__((ext_vector_type(16))) float f32x16;
typedef unsigned int u32;

// ---------------------------------------------------------------------------
// Phase A: proj = feat @ W^T (fp32 exact), row L2 norm, bf16 normalized copy
// ---------------------------------------------------------------------------
__global__ __launch_bounds__(256) void phaseA_kernel(
    const float* __restrict__ feat, const float* __restrict__ W,
    float* __restrict__ proj, __hip_bfloat16* __restrict__ nrmb) {
  __shared__ float Wl[DD][132];
  __shared__ float fl[16][DD];
  const int t = threadIdx.x;
  const int blk = blockIdx.x;     // 16 rows per block

  const f32x4* W4 = (const f32x4*)W;
#pragma unroll
  for (int i = 0; i < 16; ++i) {
    int f4 = t + 256 * i;
    *(f32x4*)&Wl[f4 >> 5][(f4 & 31) * 4] = W4[f4];
  }
  const f32x4* F4 = (const f32x4*)(feat + (size_t)blk * 16 * DD);
#pragma unroll
  for (int i = 0; i < 2; ++i) {
    int f4 = t + 256 * i;
    *(f32x4*)&fl[f4 >> 5][(f4 & 31) * 4] = F4[f4];
  }
  __syncthreads();

  const int w = t >> 6, l = t & 63;
#pragma unroll 1
  for (int q = 0; q < 4; ++q) {
    const int rloc = w * 4 + q;
    const int r = blk * 16 + rloc;
    float a0 = 0.f, a1 = 0.f;
#pragma unroll
    for (int k = 0; k < DD; k += 4) {
      f32x4 fv = *(const f32x4*)&fl[rloc][k];
      f32x4 w0 = *(const f32x4*)&Wl[l][k];
      f32x4 w1 = *(const f32x4*)&Wl[l + 64][k];
      a0 += fv[0] * w0[0] + fv[1] * w0[1] + fv[2] * w0[2] + fv[3] * w0[3];
      a1 += fv[0] * w1[0] + fv[1] * w1[1] + fv[2] * w1[2] + fv[3] * w1[3];
    }
    float n2 = a0 * a0 + a1 * a1;
#pragma unroll
    for (int o = 32; o > 0; o >>= 1) n2 += __shfl_xor(n2, o);
    float invn = 1.0f / fmaxf(sqrtf(n2), 1e-12f);
    proj[(size_t)r * DD + l] = a0;
    proj[(size_t)r * DD + l + 64] = a1;
    nrmb[(size_t)r * DD + l] = __float2bfloat16(a0 * invn);
    nrmb[(size_t)r * DD + l + 64] = __float2bfloat16(a1 * invn);
  }
}

// ---------------------------------------------------------------------------
// Phase B: swapped-operand 32x32x16 MFMA Gram + per-row top-11, software-
// pipelined (scan of tile t-1 overlaps MFMA of tile t). NSPLIT=16 -> grid
// 2048 = EXACTLY 8 blocks/CU in one round; LDS 20 KB (16 dbuf + 4 stack)
// so 8 x 20 KB fills the 160 KB CU; launch_bounds(256,8) caps VGPR at 64
// (current use 60 -- if this spills, counters show FETCH/WRITE explosion).
// Stack depth 4; overflow -> inline exec-masked LADDER11 (s_cbranch-guarded,
// rare after early tiles; tile 0 degenerates to direct-insert cost).
// Key = (bits(v+2) & ~1023) | (1023 - local_idx): one u32 compare ==
// (val desc, idx asc). Output = raw packed keys (phase C decodes).
// ---------------------------------------------------------------------------
#define LSTEP(kj) { u32 mx_ = ck > (kj) ? ck : (kj);                   \
                    ck = ck > (kj) ? (kj) : ck; (kj) = mx_; }
#define LADDER11 { LSTEP(k0) LSTEP(k1) LSTEP(k2) LSTEP(k3) LSTEP(k4) \
                   LSTEP(k5) LSTEP(k6) LSTEP(k7) LSTEP(k8) LSTEP(k9) LSTEP(k10) }

#define PUSH1(vv, off)                                                     \
  { float v_ = (vv);                                                       \
    if (v_ >= thrm2) {                                                     \
      u32 ck = (__float_as_uint(v_ + 2.0f) & 0xFFFFFC00u) |                \
               (u32)(loid - (off));                                        \
      if (cnt < 4) { StkL[cnt * 256 + t] = ck; ++cnt; }                    \
      else { LADDER11 }                                                    \
    } }

#define THRUPD                                                             \
  { float th_ = __uint_as_float(k10 & 0xFFFFFC00u);                        \
    th_ = fmaxf(th_, __shfl_xor(th_, 32));                                 \
    thrm2 = th_ - 2.0f - 1e-6f; }

#define DRAIN                                                              \
  { int c_ = cnt; cnt = 0;                                                 \
    u32 ck = 0;                                                            \
    if (c_ > 0) ck = StkL[(c_ - 1) * 256 + t];                             \
    while (__any(c_ > 0)) {                                                \
      int cn_ = c_ - 1;                                                    \
      u32 ckn_ = 0;                                                        \
      if (cn_ > 0) ckn_ = StkL[(cn_ - 1) * 256 + t];                       \
      LADDER11                                                             \
      ck = ckn_; c_ = cn_ > 0 ? cn_ : 0;                                   \
    }                                                                      \
    THRUPD }

// scan 16 acc elems of one tile: lane covers cand offsets
// {0..3,8..11,16..19,24..27} + 4*hi within the tile
#define SCAN16(ACC, TBASE)                                                 \
  { const int loid = 1023 - (TBASE) - 4 * hi;                              \
    PUSH1(ACC[0], 0)   PUSH1(ACC[1], 1)   PUSH1(ACC[2], 2)                 \
    PUSH1(ACC[3], 3)   PUSH1(ACC[4], 8)   PUSH1(ACC[5], 9)                 \
    PUSH1(ACC[6], 10)  PUSH1(ACC[7], 11)  PUSH1(ACC[8], 16)                \
    PUSH1(ACC[9], 17)  PUSH1(ACC[10], 18) PUSH1(ACC[11], 19)               \
    PUSH1(ACC[12], 24) PUSH1(ACC[13], 25) PUSH1(ACC[14], 26)               \
    PUSH1(ACC[15], 27)                                                     \
    DRAIN }

// Gram of one 32-cand tile into named acc (buffer parity P is static)
#define GRAM(ACC, P)                                                       \
  { _Pragma("unroll")                                                      \
    for (int i_ = 0; i_ < 16; ++i_) ACC[i_] = 0.f;                         \
    const char* cb_ = (const char*)&cand[P][0];                            \
    __builtin_amdgcn_s_setprio(1);                                         \
    _Pragma("unroll")                                                      \
    for (int kt = 0; kt < 8; ++kt) {                                       \
      bf16x8 cv = *(const bf16x8*)(cb_ + dso[kt]);                         \
      ACC = __builtin_amdgcn_mfma_f32_32x32x16_bf16(cv, rowF[kt], ACC,     \
                                                    0, 0, 0);              \
    }                                                                      \
    __builtin_amdgcn_s_setprio(0); }

__device__ __forceinline__ void gload_lds16(const void* g, void* l) {
  __builtin_amdgcn_global_load_lds(
      (const __attribute__((address_space(1))) unsigned int*)g,
      (__attribute__((address_space(3))) unsigned int*)l, 16, 0, 0);
}

__global__ __launch_bounds__(256, 8) void phaseB_kernel(
    const __hip_bfloat16* __restrict__ nrmb, u32* __restrict__ tk) {
  __shared__ __hip_bfloat16 cand[2][CBLK * DD];   // 2 x 8 KB
  __shared__ u32 StkL[4 * 256];                   // 4 KB -> total 20 KB
  const int t = threadIdx.x;
  const int w = t >> 6, l = t & 63;
  const int l31 = l & 31, hi = l >> 5;
  const int rb = blockIdx.x >> 4;          // 0..127 row-blocks (128 rows)
  const int cs = blockIdx.x & 15;          // col-split
  const int r0 = rb * 128 + w * 32;        // wave's 32 rows
  const int csbase = cs * COLS_PER_SPLIT;
  const unsigned short* nb = (const unsigned short*)nrmb;

  // B-operand frags: my row (r0+l31), k-chunk kt*16 + hi*8
  bf16x8 rowF[8];
#pragma unroll
  for (int kt = 0; kt < 8; ++kt)
    rowF[kt] = *(const bf16x8*)(nb + (size_t)(r0 + l31) * DD + kt * 16 + hi * 8);

  // per-lane swizzled LDS byte offsets for the 8 cand fragments (hoisted)
  const int swsalt = (l31 & 7);
  int dso[8];
#pragma unroll
  for (int kt = 0; kt < 8; ++kt)
    dso[kt] = l31 * 256 + (((kt * 2 + hi) ^ swsalt) << 4);

  u32 k0 = 0, k1 = 0, k2 = 0, k3 = 0, k4 = 0, k5 = 0,
      k6 = 0, k7 = 0, k8 = 0, k9 = 0, k10 = 0;
  int cnt = 0;
  float thrm2 = -3.0e38f;

  // wave w stages cands [w*8, w*8+8); source chunk pre-swizzled ^(cl&7)
#define STAGE(bufidx, itile)                                                  \
  {                                                                           \
    const unsigned short* srcb = nb + (size_t)(csbase + (itile)*CBLK) * DD;   \
    _Pragma("unroll")                                                         \
    for (int j = 0; j < 2; ++j) {                                             \
      int cl = w * 8 + j * 4 + (l >> 4);                                      \
      int ch = (l & 15) ^ (cl & 7);                                           \
      gload_lds16(srcb + (size_t)cl * DD + ch * 8,                            \
                  &cand[bufidx][w * 1024 + j * 512]);                         \
    }                                                                         \
  }

  STAGE(0, 0);
  __syncthreads();

  f32x16 aA, aB;
#pragma unroll 1
  for (int tt = 0; tt < NITER / 2; ++tt) {
    const int t0 = 2 * tt;
    // body 0: cand[0] holds tile t0; compute aA; scan aB = tile t0-1
    if (t0 + 1 < NITER) STAGE(1, t0 + 1);
    GRAM(aA, 0)
    if (tt > 0) { SCAN16(aB, (t0 - 1) * CBLK) }
    __syncthreads();   // tile t0+1 landed; cand[0] reads done
    // body 1: cand[1] holds tile t0+1; compute aB; scan aA = tile t0
    if (t0 + 2 < NITER) STAGE(0, t0 + 2);
    GRAM(aB, 1)
    SCAN16(aA, t0 * CBLK)
    __syncthreads();   // tile t0+2 landed; cand[1] reads done
  }
  // epilogue: scan last tile (NITER-1), still in aB
  SCAN16(aB, (NITER - 1) * CBLK)

  // merge lane <-> lane+32 partial ladders (disjoint halves of same row)
  {
    int m0 = __shfl_xor((int)k0, 32);
    int m1 = __shfl_xor((int)k1, 32);
    int m2 = __shfl_xor((int)k2, 32);
    int m3 = __shfl_xor((int)k3, 32);
    int m4 = __shfl_xor((int)k4, 32);
    int m5 = __shfl_xor((int)k5, 32);
    int m6 = __shfl_xor((int)k6, 32);
    int m7 = __shfl_xor((int)k7, 32);
    int m8 = __shfl_xor((int)k8, 32);
    int m9 = __shfl_xor((int)k9, 32);
    int m10 = __shfl_xor((int)k10, 32);
    { u32 ck = (u32)m0; LADDER11 }
    { u32 ck = (u32)m1; LADDER11 }
    { u32 ck = (u32)m2; LADDER11 }
    { u32 ck = (u32)m3; LADDER11 }
    { u32 ck = (u32)m4; LADDER11 }
    { u32 ck = (u32)m5; LADDER11 }
    { u32 ck = (u32)m6; LADDER11 }
    { u32 ck = (u32)m7; LADDER11 }
    { u32 ck = (u32)m8; LADDER11 }
    { u32 ck = (u32)m9; LADDER11 }
    { u32 ck = (u32)m10; LADDER11 }
  }

  if (hi == 0) {
    const int myr = r0 + l31;
    u32* ov = tk + ((size_t)cs * NN + myr) * KP1;
    ov[0] = k0; ov[1] = k1; ov[2] = k2; ov[3] = k3; ov[4] = k4; ov[5] = k5;
    ov[6] = k6; ov[7] = k7; ov[8] = k8; ov[9] = k9; ov[10] = k10;
  }
#undef STAGE
}

// ---------------------------------------------------------------------------
// Phase C: merge 16x11 packed-key partial top-k per row, softmax (self
// masked), gather. One wave per row; 4 rows per block. fp32 output.
// key -> value = as_float(key & ~1023) - 2 ; idx = s*1024 + 1023 - (key&1023)
// ---------------------------------------------------------------------------
__global__ __launch_bounds__(256) void phaseC_kernel(
    const float* __restrict__ proj, const float* __restrict__ feat,
    const float* __restrict__ emb, const u32* __restrict__ tk,
    float* __restrict__ out) {
  const int t = threadIdx.x, w = t >> 6, l = t & 63;
  const int r = blockIdx.x * 4 + w;

  // 176 candidates in 3 lane-slots
  float v0, v1, v2 = -3.0e38f;
  int i0, i1, i2 = 0x7fffffff;
  {
    int j = l, s = j / KP1, k = j - s * KP1;
    u32 key = tk[((size_t)s * NN + r) * KP1 + k];
    v0 = __uint_as_float(key & 0xFFFFFC00u) - 2.0f;
    i0 = (s << 10) + 1023 - (int)(key & 1023u);
  }
  {
    int j = 64 + l, s = j / KP1, k = j - s * KP1;
    u32 key = tk[((size_t)s * NN + r) * KP1 + k];
    v1 = __uint_as_float(key & 0xFFFFFC00u) - 2.0f;
    i1 = (s << 10) + 1023 - (int)(key & 1023u);
  }
  if (l < 176 - 128) {
    int j = 128 + l, s = j / KP1, k = j - s * KP1;
    u32 key = tk[((size_t)s * NN + r) * KP1 + k];
    v2 = __uint_as_float(key & 0xFFFFFC00u) - 2.0f;
    i2 = (s << 10) + 1023 - (int)(key & 1023u);
  }

  bool t0 = false, t1 = false, t2 = false;
  float selv[KP1]; int seli[KP1];
#pragma unroll
  for (int s = 0; s < KP1; ++s) {
    float bv = -3.0e38f; int bi = 0x7fffffff;
    if (!t0 && (v0 > bv || (v0 == bv && i0 < bi))) { bv = v0; bi = i0; }
    if (!t1 && (v1 > bv || (v1 == bv && i1 < bi))) { bv = v1; bi = i1; }
    if (!t2 && (v2 > bv || (v2 == bv && i2 < bi))) { bv = v2; bi = i2; }
#pragma unroll
    for (int o = 32; o > 0; o >>= 1) {
      float ovv = __shfl_xor(bv, o);
      int obi = __shfl_xor(bi, o);
      if (ovv > bv || (ovv == bv && obi < bi)) { bv = ovv; bi = obi; }
    }
    selv[s] = bv; seli[s] = bi;
    if (!t0 && i0 == bi) t0 = true;
    else if (!t1 && i1 == bi) t1 = true;
    else if (!t2 && i2 == bi) t2 = true;
  }

  float m = -3.0e38f;
#pragma unroll
  for (int s = 0; s < KP1; ++s)
    if (seli[s] != r) m = fmaxf(m, selv[s]);
  float den = 0.f; float wg[KP1];
#pragma unroll
  for (int s = 0; s < KP1; ++s) {
    float e = (seli[s] != r) ? __expf(selv[s] - m) : 0.f;
    wg[s] = e; den += e;
  }
  const float rden = 1.0f / den;

  float p0 = 0.f, p1 = 0.f;
#pragma unroll
  for (int s = 0; s < KP1; ++s) {
    const float* pr = proj + (size_t)seli[s] * DD;
    float ws = wg[s] * rden;
    p0 += ws * pr[l];
    p1 += ws * pr[l + 64];
  }
  out[(size_t)r * DD + l] = feat[(size_t)r * DD + l] + 0.1f * (p0 + emb[l]);
  out[(size_t)r * DD + l + 64] =
      feat[(size_t)r * DD + l + 64] + 0.1f * (p1 + emb[l + 64]);
}

// ---------------------------------------------------------------------------
extern "C" void kernel_launch(void* const* d_in, const int* in_sizes, int n_in,
                              void* d_out, int out_size, void* d_ws, size_t ws_size,
                              hipStream_t stream) {
  (void)in_sizes; (void)n_in; (void)out_size; (void)ws_size;
  const float* feat = (const float*)d_in[0];
  const float* W    = (const float*)d_in[1];
  const float* emb  = (const float*)d_in[2];
  float* out = (float*)d_out;

  char* ws = (char*)d_ws;
  float* proj          = (float*)ws;                                    // 8 MB
  __hip_bfloat16* nrmb = (__hip_bfloat16*)(ws + (size_t)NN * DD * 4);   // 4 MB
  u32* tk = (u32*)(ws + (size_t)NN * DD * 6);                           // 11.5 MB

  phaseA_kernel<<<NN / 16, 256, 0, stream>>>(feat, W, proj, nrmb);
  phaseB_kernel<<<128 * NSPLIT, 256, 0, stream>>>(nrmb, tk);
  phaseC_kernel<<<NN / 4, 256, 0, stream>>>(proj, feat, emb, tk, out);
}

// Round 15
// 217.641 us; speedup vs baseline: 2.3025x; 2.3025x over previous
//
#include <hip/hip_runtime.h>
#include <hip/hip_bf16.h>

#define NN 16384
#define DD 128
#define KP1 11
#define NSPLIT 8
#define CBLK 32
#define COLS_PER_SPLIT (NN / NSPLIT)   /* 2048 */
#define NITER (COLS_PER_SPLIT / CBLK)  /* 64 */

typedef __attribute__((ext_vector_type(8))) short bf16x8;
typedef __attribute__((ext_vector_type(4))) float f32x4;
typedef __attribute__((ext_vector_type(16))) float f32x16;
typedef unsigned int u32;

// ---------------------------------------------------------------------------
// Phase A: proj = feat @ W^T (fp32 exact), row L2 norm, bf16 normalized copy
// ---------------------------------------------------------------------------
__global__ __launch_bounds__(256) void phaseA_kernel(
    const float* __restrict__ feat, const float* __restrict__ W,
    float* __restrict__ proj, __hip_bfloat16* __restrict__ nrmb) {
  __shared__ float Wl[DD][132];
  __shared__ float fl[16][DD];
  const int t = threadIdx.x;
  const int blk = blockIdx.x;     // 16 rows per block

  const f32x4* W4 = (const f32x4*)W;
#pragma unroll
  for (int i = 0; i < 16; ++i) {
    int f4 = t + 256 * i;
    *(f32x4*)&Wl[f4 >> 5][(f4 & 31) * 4] = W4[f4];
  }
  const f32x4* F4 = (const f32x4*)(feat + (size_t)blk * 16 * DD);
#pragma unroll
  for (int i = 0; i < 2; ++i) {
    int f4 = t + 256 * i;
    *(f32x4*)&fl[f4 >> 5][(f4 & 31) * 4] = F4[f4];
  }
  __syncthreads();

  const int w = t >> 6, l = t & 63;
#pragma unroll 1
  for (int q = 0; q < 4; ++q) {
    const int rloc = w * 4 + q;
    const int r = blk * 16 + rloc;
    float a0 = 0.f, a1 = 0.f;
#pragma unroll
    for (int k = 0; k < DD; k += 4) {
      f32x4 fv = *(const f32x4*)&fl[rloc][k];
      f32x4 w0 = *(const f32x4*)&Wl[l][k];
      f32x4 w1 = *(const f32x4*)&Wl[l + 64][k];
      a0 += fv[0] * w0[0] + fv[1] * w0[1] + fv[2] * w0[2] + fv[3] * w0[3];
      a1 += fv[0] * w1[0] + fv[1] * w1[1] + fv[2] * w1[2] + fv[3] * w1[3];
    }
    float n2 = a0 * a0 + a1 * a1;
#pragma unroll
    for (int o = 32; o > 0; o >>= 1) n2 += __shfl_xor(n2, o);
    float invn = 1.0f / fmaxf(sqrtf(n2), 1e-12f);
    proj[(size_t)r * DD + l] = a0;
    proj[(size_t)r * DD + l + 64] = a1;
    nrmb[(size_t)r * DD + l] = __float2bfloat16(a0 * invn);
    nrmb[(size_t)r * DD + l + 64] = __float2bfloat16(a1 * invn);
  }
}

// ---------------------------------------------------------------------------
// Phase B: swapped-operand 32x32x16 MFMA Gram + per-row top-11, software-
// pipelined (scan of tile t-1 in regs aB/aA overlaps the MFMA chain of
// tile t). One DRAIN (with threshold update) per tile, depth-16 LDS stack
// (overflow impossible). NSPLIT=8 -> grid 1024 = exactly 4 blocks/CU in one
// round. True register budget = VGPR 60 + AGPR 32 ~ 92 -> 4 waves/SIMD is
// the occupancy ceiling (m69 bands); do NOT coerce past it (r9/r14 spilled).
// s_setprio(1) around the MFMA cluster (T5; blocks on a SIMD are unsynced).
// Key = (bits(v+2) & ~2047) | (2047 - local_idx): one u32 compare ==
// (val desc, idx asc) == jax.lax.top_k tie semantics. Output = packed keys.
// ---------------------------------------------------------------------------
#define LSTEP(kj) { u32 mx_ = ck > (kj) ? ck : (kj);                   \
                    ck = ck > (kj) ? (kj) : ck; (kj) = mx_; }
#define LADDER11 { LSTEP(k0) LSTEP(k1) LSTEP(k2) LSTEP(k3) LSTEP(k4) \
                   LSTEP(k5) LSTEP(k6) LSTEP(k7) LSTEP(k8) LSTEP(k9) LSTEP(k10) }

#define PUSH1(vv, off)                                                     \
  { float v_ = (vv);                                                       \
    if (v_ >= thrm2) {                                                     \
      u32 ck = (__float_as_uint(v_ + 2.0f) & 0xFFFFF800u) |                \
               (u32)(loid - (off));                                        \
      StkL[cnt * 256 + t] = ck; ++cnt;                                     \
    } }

#define THRUPD                                                             \
  { float th_ = __uint_as_float(k10 & 0xFFFFF800u);                        \
    th_ = fmaxf(th_, __shfl_xor(th_, 32));                                 \
    thrm2 = th_ - 2.0f - 1e-6f; }

#define DRAIN                                                              \
  { int c_ = cnt; cnt = 0;                                                 \
    u32 ck = 0;                                                            \
    if (c_ > 0) ck = StkL[(c_ - 1) * 256 + t];                             \
    while (__any(c_ > 0)) {                                                \
      int cn_ = c_ - 1;                                                    \
      u32 ckn_ = 0;                                                        \
      if (cn_ > 0) ckn_ = StkL[(cn_ - 1) * 256 + t];                       \
      LADDER11                                                             \
      ck = ckn_; c_ = cn_ > 0 ? cn_ : 0;                                   \
    }                                                                      \
    THRUPD }

// scan 16 acc elems of one tile: lane covers cand offsets
// {0..3,8..11,16..19,24..27} + 4*hi within the tile
#define SCAN16(ACC, TBASE)                                                 \
  { const int loid = 2047 - (TBASE) - 4 * hi;                              \
    PUSH1(ACC[0], 0)   PUSH1(ACC[1], 1)   PUSH1(ACC[2], 2)                 \
    PUSH1(ACC[3], 3)   PUSH1(ACC[4], 8)   PUSH1(ACC[5], 9)                 \
    PUSH1(ACC[6], 10)  PUSH1(ACC[7], 11)  PUSH1(ACC[8], 16)                \
    PUSH1(ACC[9], 17)  PUSH1(ACC[10], 18) PUSH1(ACC[11], 19)               \
    PUSH1(ACC[12], 24) PUSH1(ACC[13], 25) PUSH1(ACC[14], 26)               \
    PUSH1(ACC[15], 27)                                                     \
    DRAIN }

// Gram of one 32-cand tile into named acc (buffer parity P is static)
#define GRAM(ACC, P)                                                       \
  { _Pragma("unroll")                                                      \
    for (int i_ = 0; i_ < 16; ++i_) ACC[i_] = 0.f;                         \
    const char* cb_ = (const char*)&cand[P][0];                            \
    __builtin_amdgcn_s_setprio(1);                                         \
    _Pragma("unroll")                                                      \
    for (int kt = 0; kt < 8; ++kt) {                                       \
      bf16x8 cv = *(const bf16x8*)(cb_ + dso[kt]);                         \
      ACC = __builtin_amdgcn_mfma_f32_32x32x16_bf16(cv, rowF[kt], ACC,     \
                                                    0, 0, 0);              \
    }                                                                      \
    __builtin_amdgcn_s_setprio(0); }

__device__ __forceinline__ void gload_lds16(const void* g, void* l) {
  __builtin_amdgcn_global_load_lds(
      (const __attribute__((address_space(1))) unsigned int*)g,
      (__attribute__((address_space(3))) unsigned int*)l, 16, 0, 0);
}

__global__ __launch_bounds__(256, 4) void phaseB_kernel(
    const __hip_bfloat16* __restrict__ nrmb, u32* __restrict__ tk) {
  __shared__ __hip_bfloat16 cand[2][CBLK * DD];   // 2 x 8 KB
  __shared__ u32 StkL[16 * 256];                  // 16 KB -> total 32 KB
  const int t = threadIdx.x;
  const int w = t >> 6, l = t & 63;
  const int l31 = l & 31, hi = l >> 5;
  const int rb = blockIdx.x >> 3;          // 0..127 row-blocks (128 rows)
  const int cs = blockIdx.x & 7;           // col-split
  const int r0 = rb * 128 + w * 32;        // wave's 32 rows
  const int csbase = cs * COLS_PER_SPLIT;
  const unsigned short* nb = (const unsigned short*)nrmb;

  // B-operand frags: my row (r0+l31), k-chunk kt*16 + hi*8
  bf16x8 rowF[8];
#pragma unroll
  for (int kt = 0; kt < 8; ++kt)
    rowF[kt] = *(const bf16x8*)(nb + (size_t)(r0 + l31) * DD + kt * 16 + hi * 8);

  // per-lane swizzled LDS byte offsets for the 8 cand fragments (hoisted)
  const int swsalt = (l31 & 7);
  int dso[8];
#pragma unroll
  for (int kt = 0; kt < 8; ++kt)
    dso[kt] = l31 * 256 + (((kt * 2 + hi) ^ swsalt) << 4);

  u32 k0 = 0, k1 = 0, k2 = 0, k3 = 0, k4 = 0, k5 = 0,
      k6 = 0, k7 = 0, k8 = 0, k9 = 0, k10 = 0;
  int cnt = 0;
  float thrm2 = -3.0e38f;

  // wave w stages cands [w*8, w*8+8); source chunk pre-swizzled ^(cl&7)
#define STAGE(bufidx, itile)                                                  \
  {                                                                           \
    const unsigned short* srcb = nb + (size_t)(csbase + (itile)*CBLK) * DD;   \
    _Pragma("unroll")                                                         \
    for (int j = 0; j < 2; ++j) {                                             \
      int cl = w * 8 + j * 4 + (l >> 4);                                      \
      int ch = (l & 15) ^ (cl & 7);                                           \
      gload_lds16(srcb + (size_t)cl * DD + ch * 8,                            \
                  &cand[bufidx][w * 1024 + j * 512]);                         \
    }                                                                         \
  }

  STAGE(0, 0);
  __syncthreads();

  f32x16 aA, aB;
#pragma unroll 1
  for (int tt = 0; tt < NITER / 2; ++tt) {
    const int t0 = 2 * tt;
    // body 0: cand[0] holds tile t0; compute aA; scan aB = tile t0-1
    if (t0 + 1 < NITER) STAGE(1, t0 + 1);
    GRAM(aA, 0)
    if (tt > 0) { SCAN16(aB, (t0 - 1) * CBLK) }
    __syncthreads();   // tile t0+1 landed; cand[0] reads done
    // body 1: cand[1] holds tile t0+1; compute aB; scan aA = tile t0
    if (t0 + 2 < NITER) STAGE(0, t0 + 2);
    GRAM(aB, 1)
    SCAN16(aA, t0 * CBLK)
    __syncthreads();   // tile t0+2 landed; cand[1] reads done
  }
  // epilogue: scan last tile (NITER-1), still in aB
  SCAN16(aB, (NITER - 1) * CBLK)

  // merge lane <-> lane+32 partial ladders (disjoint halves of same row)
  {
    int m0 = __shfl_xor((int)k0, 32);
    int m1 = __shfl_xor((int)k1, 32);
    int m2 = __shfl_xor((int)k2, 32);
    int m3 = __shfl_xor((int)k3, 32);
    int m4 = __shfl_xor((int)k4, 32);
    int m5 = __shfl_xor((int)k5, 32);
    int m6 = __shfl_xor((int)k6, 32);
    int m7 = __shfl_xor((int)k7, 32);
    int m8 = __shfl_xor((int)k8, 32);
    int m9 = __shfl_xor((int)k9, 32);
    int m10 = __shfl_xor((int)k10, 32);
    { u32 ck = (u32)m0; LADDER11 }
    { u32 ck = (u32)m1; LADDER11 }
    { u32 ck = (u32)m2; LADDER11 }
    { u32 ck = (u32)m3; LADDER11 }
    { u32 ck = (u32)m4; LADDER11 }
    { u32 ck = (u32)m5; LADDER11 }
    { u32 ck = (u32)m6; LADDER11 }
    { u32 ck = (u32)m7; LADDER11 }
    { u32 ck = (u32)m8; LADDER11 }
    { u32 ck = (u32)m9; LADDER11 }
    { u32 ck = (u32)m10; LADDER11 }
  }

  if (hi == 0) {
    const int myr = r0 + l31;
    u32* ov = tk + ((size_t)cs * NN + myr) * KP1;
    ov[0] = k0; ov[1] = k1; ov[2] = k2; ov[3] = k3; ov[4] = k4; ov[5] = k5;
    ov[6] = k6; ov[7] = k7; ov[8] = k8; ov[9] = k9; ov[10] = k10;
  }
#undef STAGE
}

// ---------------------------------------------------------------------------
// Phase C: merge 8x11 packed-key partial top-k per row, softmax (self
// masked), gather. One wave per row; 4 rows per block. fp32 output.
// key -> value = as_float(key & ~2047) - 2 ; idx = s*2048 + 2047 - (key&2047)
// ---------------------------------------------------------------------------
__global__ __launch_bounds__(256) void phaseC_kernel(
    const float* __restrict__ proj, const float* __restrict__ feat,
    const float* __restrict__ emb, const u32* __restrict__ tk,
    float* __restrict__ out) {
  const int t = threadIdx.x, w = t >> 6, l = t & 63;
  const int r = blockIdx.x * 4 + w;

  // 88 candidates in 2 lane-slots
  float v0, v1 = -3.0e38f;
  int i0, i1 = 0x7fffffff;
  {
    int j = l, s = j / KP1, k = j - s * KP1;
    u32 key = tk[((size_t)s * NN + r) * KP1 + k];
    v0 = __uint_as_float(key & 0xFFFFF800u) - 2.0f;
    i0 = (s << 11) + 2047 - (int)(key & 2047u);
  }
  if (l < 88 - 64) {
    int j = 64 + l, s = j / KP1, k = j - s * KP1;
    u32 key = tk[((size_t)s * NN + r) * KP1 + k];
    v1 = __uint_as_float(key & 0xFFFFF800u) - 2.0f;
    i1 = (s << 11) + 2047 - (int)(key & 2047u);
  }

  bool t0 = false, t1 = false;
  float selv[KP1]; int seli[KP1];
#pragma unroll
  for (int s = 0; s < KP1; ++s) {
    float bv = -3.0e38f; int bi = 0x7fffffff;
    if (!t0 && (v0 > bv || (v0 == bv && i0 < bi))) { bv = v0; bi = i0; }
    if (!t1 && (v1 > bv || (v1 == bv && i1 < bi))) { bv = v1; bi = i1; }
#pragma unroll
    for (int o = 32; o > 0; o >>= 1) {
      float ovv = __shfl_xor(bv, o);
      int obi = __shfl_xor(bi, o);
      if (ovv > bv || (ovv == bv && obi < bi)) { bv = ovv; bi = obi; }
    }
    selv[s] = bv; seli[s] = bi;
    if (!t0 && i0 == bi) t0 = true;
    else if (!t1 && i1 == bi) t1 = true;
  }

  float m = -3.0e38f;
#pragma unroll
  for (int s = 0; s < KP1; ++s)
    if (seli[s] != r) m = fmaxf(m, selv[s]);
  float den = 0.f; float wg[KP1];
#pragma unroll
  for (int s = 0; s < KP1; ++s) {
    float e = (seli[s] != r) ? __expf(selv[s] - m) : 0.f;
    wg[s] = e; den += e;
  }
  const float rden = 1.0f / den;

  float p0 = 0.f, p1 = 0.f;
#pragma unroll
  for (int s = 0; s < KP1; ++s) {
    const float* pr = proj + (size_t)seli[s] * DD;
    float ws = wg[s] * rden;
    p0 += ws * pr[l];
    p1 += ws * pr[l + 64];
  }
  out[(size_t)r * DD + l] = feat[(size_t)r * DD + l] + 0.1f * (p0 + emb[l]);
  out[(size_t)r * DD + l + 64] =
      feat[(size_t)r * DD + l + 64] + 0.1f * (p1 + emb[l + 64]);
}

// ---------------------------------------------------------------------------
extern "C" void kernel_launch(void* const* d_in, const int* in_sizes, int n_in,
                              void* d_out, int out_size, void* d_ws, size_t ws_size,
                              hipStream_t stream) {
  (void)in_sizes; (void)n_in; (void)out_size; (void)ws_size;
  const float* feat = (const float*)d_in[0];
  const float* W    = (const float*)d_in[1];
  const float* emb  = (const float*)d_in[2];
  float* out = (float*)d_out;

  char* ws = (char*)d_ws;
  float* proj          = (float*)ws;                                    // 8 MB
  __hip_bfloat16* nrmb = (__hip_bfloat16*)(ws + (size_t)NN * DD * 4);   // 4 MB
  u32* tk = (u32*)(ws + (size_t)NN * DD * 6);                           // 5.77 MB

  phaseA_kernel<<<NN / 16, 256, 0, stream>>>(feat, W, proj, nrmb);
  phaseB_kernel<<<128 * NSPLIT, 256, 0, stream>>>(nrmb, tk);
  phaseC_kernel<<<NN / 4, 256, 0, stream>>>(proj, feat, emb, tk, out);
}

// Round 16
// 203.550 us; speedup vs baseline: 2.4619x; 1.0692x over previous
//
#include <hip/hip_runtime.h>
#include <hip/hip_bf16.h>

#define NN 16384
#define DD 128
#define KP1 11
#define NSPLIT 8
#define CBLK 32
#define COLS_PER_SPLIT (NN / NSPLIT)   /* 2048 */
#define NITER (COLS_PER_SPLIT / CBLK)  /* 64 */

typedef __attribute__((ext_vector_type(8))) short bf16x8;
typedef __attribute__((ext_vector_type(4))) float f32x4;
typedef __attribute__((ext_vector_type(16))) float f32x16;
typedef unsigned int u32;

// ---------------------------------------------------------------------------
// Phase A: proj = feat @ W^T (fp32 exact), row L2 norm, bf16 normalized copy
// ---------------------------------------------------------------------------
__global__ __launch_bounds__(256) void phaseA_kernel(
    const float* __restrict__ feat, const float* __restrict__ W,
    float* __restrict__ proj, __hip_bfloat16* __restrict__ nrmb) {
  __shared__ float Wl[DD][132];
  __shared__ float fl[16][DD];
  const int t = threadIdx.x;
  const int blk = blockIdx.x;     // 16 rows per block

  const f32x4* W4 = (const f32x4*)W;
#pragma unroll
  for (int i = 0; i < 16; ++i) {
    int f4 = t + 256 * i;
    *(f32x4*)&Wl[f4 >> 5][(f4 & 31) * 4] = W4[f4];
  }
  const f32x4* F4 = (const f32x4*)(feat + (size_t)blk * 16 * DD);
#pragma unroll
  for (int i = 0; i < 2; ++i) {
    int f4 = t + 256 * i;
    *(f32x4*)&fl[f4 >> 5][(f4 & 31) * 4] = F4[f4];
  }
  __syncthreads();

  const int w = t >> 6, l = t & 63;
#pragma unroll 1
  for (int q = 0; q < 4; ++q) {
    const int rloc = w * 4 + q;
    const int r = blk * 16 + rloc;
    float a0 = 0.f, a1 = 0.f;
#pragma unroll
    for (int k = 0; k < DD; k += 4) {
      f32x4 fv = *(const f32x4*)&fl[rloc][k];
      f32x4 w0 = *(const f32x4*)&Wl[l][k];
      f32x4 w1 = *(const f32x4*)&Wl[l + 64][k];
      a0 += fv[0] * w0[0] + fv[1] * w0[1] + fv[2] * w0[2] + fv[3] * w0[3];
      a1 += fv[0] * w1[0] + fv[1] * w1[1] + fv[2] * w1[2] + fv[3] * w1[3];
    }
    float n2 = a0 * a0 + a1 * a1;
#pragma unroll
    for (int o = 32; o > 0; o >>= 1) n2 += __shfl_xor(n2, o);
    float invn = 1.0f / fmaxf(sqrtf(n2), 1e-12f);
    proj[(size_t)r * DD + l] = a0;
    proj[(size_t)r * DD + l + 64] = a1;
    nrmb[(size_t)r * DD + l] = __float2bfloat16(a0 * invn);
    nrmb[(size_t)r * DD + l + 64] = __float2bfloat16(a1 * invn);
  }
}

// ---------------------------------------------------------------------------
// Phase B: swapped-operand 32x32x16 MFMA Gram + per-row top-11 via a
// BRANCHLESS med3 insert ladder: inserting ck into the descending sorted
// list {k0>=...>=k10} is k0'=max(ck,k0); kj'=v_med3_u32(ck,kj,k_{j-1}) --
// all 11 positions independent (depth 1), and ck<k10 is automatically a
// no-op, so NO filter/stack/drain/threshold machinery exists at all.
// 14 branchless VALU per candidate; zero divergence; zero LDS scan traffic.
// Software pipeline kept: scan of tile t-1 (regs aB/aA) overlaps the MFMA
// chain of tile t; s_setprio(1) around the MFMA cluster (T5).
// NSPLIT=8 -> grid 1024 = exactly 4 blocks/CU (register budget VGPR+AGPR
// ~90 caps 4 waves/SIMD -- r9/r14 proved coercing past it spills).
// Key = (bits(v+2) & ~2047) | (2047 - local_idx): one u32 compare ==
// (val desc, idx asc) == jax.lax.top_k tie semantics. Output = packed keys.
// ---------------------------------------------------------------------------
#define LADDM(CKE)                                                         \
  { u32 ck = (CKE);                                                        \
    u32 n0 = k0 > ck ? k0 : ck;                                            \
    u32 n1, n2, n3, n4, n5, n6, n7, n8, n9, n10;                           \
    asm("v_med3_u32 %0,%1,%2,%3" : "=v"(n1) : "v"(ck), "v"(k1), "v"(k0));  \
    asm("v_med3_u32 %0,%1,%2,%3" : "=v"(n2) : "v"(ck), "v"(k2), "v"(k1));  \
    asm("v_med3_u32 %0,%1,%2,%3" : "=v"(n3) : "v"(ck), "v"(k3), "v"(k2));  \
    asm("v_med3_u32 %0,%1,%2,%3" : "=v"(n4) : "v"(ck), "v"(k4), "v"(k3));  \
    asm("v_med3_u32 %0,%1,%2,%3" : "=v"(n5) : "v"(ck), "v"(k5), "v"(k4));  \
    asm("v_med3_u32 %0,%1,%2,%3" : "=v"(n6) : "v"(ck), "v"(k6), "v"(k5));  \
    asm("v_med3_u32 %0,%1,%2,%3" : "=v"(n7) : "v"(ck), "v"(k7), "v"(k6));  \
    asm("v_med3_u32 %0,%1,%2,%3" : "=v"(n8) : "v"(ck), "v"(k8), "v"(k7));  \
    asm("v_med3_u32 %0,%1,%2,%3" : "=v"(n9) : "v"(ck), "v"(k9), "v"(k8));  \
    asm("v_med3_u32 %0,%1,%2,%3" : "=v"(n10) : "v"(ck), "v"(k10), "v"(k9));\
    k0 = n0; k1 = n1; k2 = n2; k3 = n3; k4 = n4; k5 = n5;                  \
    k6 = n6; k7 = n7; k8 = n8; k9 = n9; k10 = n10; }

#define INS1(vv, off)                                                      \
  LADDM(((__float_as_uint((vv) + 2.0f) & 0xFFFFF800u) |                    \
         (u32)(loid - (off))))

// scan 16 acc elems of one tile: lane covers cand offsets
// {0..3,8..11,16..19,24..27} + 4*hi within the tile
#define SCAN16(ACC, TBASE)                                                 \
  { const int loid = 2047 - (TBASE) - 4 * hi;                              \
    INS1(ACC[0], 0)   INS1(ACC[1], 1)   INS1(ACC[2], 2)                    \
    INS1(ACC[3], 3)   INS1(ACC[4], 8)   INS1(ACC[5], 9)                    \
    INS1(ACC[6], 10)  INS1(ACC[7], 11)  INS1(ACC[8], 16)                   \
    INS1(ACC[9], 17)  INS1(ACC[10], 18) INS1(ACC[11], 19)                  \
    INS1(ACC[12], 24) INS1(ACC[13], 25) INS1(ACC[14], 26)                  \
    INS1(ACC[15], 27) }

// Gram of one 32-cand tile into named acc (buffer parity P is static)
#define GRAM(ACC, P)                                                       \
  { _Pragma("unroll")                                                      \
    for (int i_ = 0; i_ < 16; ++i_) ACC[i_] = 0.f;                         \
    const char* cb_ = (const char*)&cand[P][0];                            \
    __builtin_amdgcn_s_setprio(1);                                         \
    _Pragma("unroll")                                                      \
    for (int kt = 0; kt < 8; ++kt) {                                       \
      bf16x8 cv = *(const bf16x8*)(cb_ + dso[kt]);                         \
      ACC = __builtin_amdgcn_mfma_f32_32x32x16_bf16(cv, rowF[kt], ACC,     \
                                                    0, 0, 0);              \
    }                                                                      \
    __builtin_amdgcn_s_setprio(0); }

__device__ __forceinline__ void gload_lds16(const void* g, void* l) {
  __builtin_amdgcn_global_load_lds(
      (const __attribute__((address_space(1))) unsigned int*)g,
      (__attribute__((address_space(3))) unsigned int*)l, 16, 0, 0);
}

__global__ __launch_bounds__(256, 4) void phaseB_kernel(
    const __hip_bfloat16* __restrict__ nrmb, u32* __restrict__ tk) {
  __shared__ __hip_bfloat16 cand[2][CBLK * DD];   // 2 x 8 KB = 16 KB total
  const int t = threadIdx.x;
  const int w = t >> 6, l = t & 63;
  const int l31 = l & 31, hi = l >> 5;
  const int rb = blockIdx.x >> 3;          // 0..127 row-blocks (128 rows)
  const int cs = blockIdx.x & 7;           // col-split
  const int r0 = rb * 128 + w * 32;        // wave's 32 rows
  const int csbase = cs * COLS_PER_SPLIT;
  const unsigned short* nb = (const unsigned short*)nrmb;

  // B-operand frags: my row (r0+l31), k-chunk kt*16 + hi*8
  bf16x8 rowF[8];
#pragma unroll
  for (int kt = 0; kt < 8; ++kt)
    rowF[kt] = *(const bf16x8*)(nb + (size_t)(r0 + l31) * DD + kt * 16 + hi * 8);

  // per-lane swizzled LDS byte offsets for the 8 cand fragments (hoisted)
  const int swsalt = (l31 & 7);
  int dso[8];
#pragma unroll
  for (int kt = 0; kt < 8; ++kt)
    dso[kt] = l31 * 256 + (((kt * 2 + hi) ^ swsalt) << 4);

  u32 k0 = 0, k1 = 0, k2 = 0, k3 = 0, k4 = 0, k5 = 0,
      k6 = 0, k7 = 0, k8 = 0, k9 = 0, k10 = 0;

  // wave w stages cands [w*8, w*8+8); source chunk pre-swizzled ^(cl&7)
#define STAGE(bufidx, itile)                                                  \
  {                                                                           \
    const unsigned short* srcb = nb + (size_t)(csbase + (itile)*CBLK) * DD;   \
    _Pragma("unroll")                                                         \
    for (int j = 0; j < 2; ++j) {                                             \
      int cl = w * 8 + j * 4 + (l >> 4);                                      \
      int ch = (l & 15) ^ (cl & 7);                                           \
      gload_lds16(srcb + (size_t)cl * DD + ch * 8,                            \
                  &cand[bufidx][w * 1024 + j * 512]);                         \
    }                                                                         \
  }

  STAGE(0, 0);
  __syncthreads();

  f32x16 aA, aB;
#pragma unroll 1
  for (int tt = 0; tt < NITER / 2; ++tt) {
    const int t0 = 2 * tt;
    // body 0: cand[0] holds tile t0; compute aA; scan aB = tile t0-1
    if (t0 + 1 < NITER) STAGE(1, t0 + 1);
    GRAM(aA, 0)
    if (tt > 0) { SCAN16(aB, (t0 - 1) * CBLK) }
    __syncthreads();   // tile t0+1 landed; cand[0] reads done
    // body 1: cand[1] holds tile t0+1; compute aB; scan aA = tile t0
    if (t0 + 2 < NITER) STAGE(0, t0 + 2);
    GRAM(aB, 1)
    SCAN16(aA, t0 * CBLK)
    __syncthreads();   // tile t0+2 landed; cand[1] reads done
  }
  // epilogue: scan last tile (NITER-1), still in aB
  SCAN16(aB, (NITER - 1) * CBLK)

  // merge lane <-> lane+32 partial ladders (disjoint halves of same row)
  {
    int m0 = __shfl_xor((int)k0, 32);
    int m1 = __shfl_xor((int)k1, 32);
    int m2 = __shfl_xor((int)k2, 32);
    int m3 = __shfl_xor((int)k3, 32);
    int m4 = __shfl_xor((int)k4, 32);
    int m5 = __shfl_xor((int)k5, 32);
    int m6 = __shfl_xor((int)k6, 32);
    int m7 = __shfl_xor((int)k7, 32);
    int m8 = __shfl_xor((int)k8, 32);
    int m9 = __shfl_xor((int)k9, 32);
    int m10 = __shfl_xor((int)k10, 32);
    LADDM((u32)m0)
    LADDM((u32)m1)
    LADDM((u32)m2)
    LADDM((u32)m3)
    LADDM((u32)m4)
    LADDM((u32)m5)
    LADDM((u32)m6)
    LADDM((u32)m7)
    LADDM((u32)m8)
    LADDM((u32)m9)
    LADDM((u32)m10)
  }

  if (hi == 0) {
    const int myr = r0 + l31;
    u32* ov = tk + ((size_t)cs * NN + myr) * KP1;
    ov[0] = k0; ov[1] = k1; ov[2] = k2; ov[3] = k3; ov[4] = k4; ov[5] = k5;
    ov[6] = k6; ov[7] = k7; ov[8] = k8; ov[9] = k9; ov[10] = k10;
  }
#undef STAGE
}

// ---------------------------------------------------------------------------
// Phase C: merge 8x11 packed-key partial top-k per row, softmax (self
// masked), gather. One wave per row; 4 rows per block. fp32 output.
// key -> value = as_float(key & ~2047) - 2 ; idx = s*2048 + 2047 - (key&2047)
// ---------------------------------------------------------------------------
__global__ __launch_bounds__(256) void phaseC_kernel(
    const float* __restrict__ proj, const float* __restrict__ feat,
    const float* __restrict__ emb, const u32* __restrict__ tk,
    float* __restrict__ out) {
  const int t = threadIdx.x, w = t >> 6, l = t & 63;
  const int r = blockIdx.x * 4 + w;

  // 88 candidates in 2 lane-slots
  float v0, v1 = -3.0e38f;
  int i0, i1 = 0x7fffffff;
  {
    int j = l, s = j / KP1, k = j - s * KP1;
    u32 key = tk[((size_t)s * NN + r) * KP1 + k];
    v0 = __uint_as_float(key & 0xFFFFF800u) - 2.0f;
    i0 = (s << 11) + 2047 - (int)(key & 2047u);
  }
  if (l < 88 - 64) {
    int j = 64 + l, s = j / KP1, k = j - s * KP1;
    u32 key = tk[((size_t)s * NN + r) * KP1 + k];
    v1 = __uint_as_float(key & 0xFFFFF800u) - 2.0f;
    i1 = (s << 11) + 2047 - (int)(key & 2047u);
  }

  bool t0 = false, t1 = false;
  float selv[KP1]; int seli[KP1];
#pragma unroll
  for (int s = 0; s < KP1; ++s) {
    float bv = -3.0e38f; int bi = 0x7fffffff;
    if (!t0 && (v0 > bv || (v0 == bv && i0 < bi))) { bv = v0; bi = i0; }
    if (!t1 && (v1 > bv || (v1 == bv && i1 < bi))) { bv = v1; bi = i1; }
#pragma unroll
    for (int o = 32; o > 0; o >>= 1) {
      float ovv = __shfl_xor(bv, o);
      int obi = __shfl_xor(bi, o);
      if (ovv > bv || (ovv == bv && obi < bi)) { bv = ovv; bi = obi; }
    }
    selv[s] = bv; seli[s] = bi;
    if (!t0 && i0 == bi) t0 = true;
    else if (!t1 && i1 == bi) t1 = true;
  }

  float m = -3.0e38f;
#pragma unroll
  for (int s = 0; s < KP1; ++s)
    if (seli[s] != r) m = fmaxf(m, selv[s]);
  float den = 0.f; float wg[KP1];
#pragma unroll
  for (int s = 0; s < KP1; ++s) {
    float e = (seli[s] != r) ? __expf(selv[s] - m) : 0.f;
    wg[s] = e; den += e;
  }
  const float rden = 1.0f / den;

  float p0 = 0.f, p1 = 0.f;
#pragma unroll
  for (int s = 0; s < KP1; ++s) {
    const float* pr = proj + (size_t)seli[s] * DD;
    float ws = wg[s] * rden;
    p0 += ws * pr[l];
    p1 += ws * pr[l + 64];
  }
  out[(size_t)r * DD + l] = feat[(size_t)r * DD + l] + 0.1f * (p0 + emb[l]);
  out[(size_t)r * DD + l + 64] =
      feat[(size_t)r * DD + l + 64] + 0.1f * (p1 + emb[l + 64]);
}

// ---------------------------------------------------------------------------
extern "C" void kernel_launch(void* const* d_in, const int* in_sizes, int n_in,
                              void* d_out, int out_size, void* d_ws, size_t ws_size,
                              hipStream_t stream) {
  (void)in_sizes; (void)n_in; (void)out_size; (void)ws_size;
  const float* feat = (const float*)d_in[0];
  const float* W    = (const float*)d_in[1];
  const float* emb  = (const float*)d_in[2];
  float* out = (float*)d_out;

  char* ws = (char*)d_ws;
  float* proj          = (float*)ws;                                    // 8 MB
  __hip_bfloat16* nrmb = (__hip_bfloat16*)(ws + (size_t)NN * DD * 4);   // 4 MB
  u32* tk = (u32*)(ws + (size_t)NN * DD * 6);                           // 5.77 MB

  phaseA_kernel<<<NN / 16, 256, 0, stream>>>(feat, W, proj, nrmb);
  phaseB_kernel<<<128 * NSPLIT, 256, 0, stream>>>(nrmb, tk);
  phaseC_kernel<<<NN / 4, 256, 0, stream>>>(proj, feat, emb, tk, out);
}